// Round 1
// baseline (594.972 us; speedup 1.0000x reference)
//
#include <hip/hip_runtime.h>
#include <stdint.h>

#define B_ 8
#define D_ 4096
#define H_ 32
#define HD_ 128
#define KV_ 512
#define PAST_ 8191
#define SCALE_ 0.08838834764831845f  // 128^-0.5

// workspace layout (float offsets)
#define OFF_QABS 0u
#define OFF_CNEW 131072u            // 8*32*512
#define OFF_ML   135168u            // +8*512
#define OFF_CTXP 167936u            // +8*64*64
#define OFF_CTX  8556544u           // +8*64*32*512
#define OFF_CTX2 8687616u           // +8*32*512
// total 8720384 floats = 33.3 MB

typedef float f32x4 __attribute__((ext_vector_type(4)));
typedef float f32x2 __attribute__((ext_vector_type(2)));
typedef short s16x8 __attribute__((ext_vector_type(8)));
typedef short s16x4 __attribute__((ext_vector_type(4)));

__device__ __forceinline__ unsigned short f2bf(float f) {
    unsigned u = __float_as_uint(f);
    u = (u + 0x7FFFu + ((u >> 16) & 1u)) >> 16;
    return (unsigned short)u;
}
__device__ __forceinline__ float bf2f(unsigned short s) {
    return __uint_as_float(((unsigned)s) << 16);
}

// ---------------- Kernel A: q_abs = x @ absorbed_qk (per head), c_new = x @ w_compress
// grid (33, 8): blockIdx.x = h (32 == compress), blockIdx.y = d-chunk of 512
__global__ __launch_bounds__(256) void k_qabs(const float* __restrict__ x,
                                              const float* __restrict__ aqk,
                                              const float* __restrict__ wc,
                                              float* __restrict__ ws) {
    const int h = blockIdx.x;
    const int dc = blockIdx.y;
    const int t = threadIdx.x;
    alignas(16) __shared__ float x_lds[B_][512];
    for (int i = t; i < B_ * 512; i += 256) {
        const int b = i >> 9, dd = i & 511;
        x_lds[b][dd] = x[b * D_ + dc * 512 + dd];
    }
    __syncthreads();
    const float* A = (h < H_) ? (aqk + (size_t)h * D_ * KV_) : wc;
    A += (size_t)(dc * 512) * KV_ + 2 * t;

    float acc[B_][2] = {};
    for (int dd = 0; dd < 512; dd += 4) {
        f32x2 a[4];
#pragma unroll
        for (int i = 0; i < 4; ++i)
            a[i] = *(const f32x2*)(A + (size_t)(dd + i) * KV_);
#pragma unroll
        for (int b = 0; b < B_; ++b) {
            const f32x4 xv = *(const f32x4*)&x_lds[b][dd];
            acc[b][0] += xv[0] * a[0][0] + xv[1] * a[1][0] + xv[2] * a[2][0] + xv[3] * a[3][0];
            acc[b][1] += xv[0] * a[0][1] + xv[1] * a[1][1] + xv[2] * a[2][1] + xv[3] * a[3][1];
        }
    }
#pragma unroll
    for (int b = 0; b < B_; ++b) {
        float* dst = (h < H_) ? (ws + OFF_QABS + (size_t)(b * H_ + h) * KV_ + 2 * t)
                              : (ws + OFF_CNEW + (size_t)b * KV_ + 2 * t);
        atomicAdd(dst, acc[b][0]);
        atomicAdd(dst + 1, acc[b][1]);
    }
}

// ---------------- Kernel B: split-KV flash attention over compressed cache
// grid 512: block = (b, sc) ; chunk = 128 s, sub-chunks of 16 s
__global__ __launch_bounds__(256, 2) void k_attn(const float* __restrict__ past_c,
                                                 float* __restrict__ ws) {
    const int bx = blockIdx.x;
    const int b = bx >> 6, sc = bx & 63;
    const int t = threadIdx.x;
    const int w = t >> 6, lane = t & 63, quad = lane >> 4, ln = lane & 15;
    const int ni = w & 1, kh = w >> 1;

    alignas(16) __shared__ unsigned short ch[16 * 520];   // c hi, row-major [s][k]
    alignas(16) __shared__ unsigned short cl[16 * 520];   // c lo
    alignas(16) __shared__ unsigned short cT[512 * 20];   // c hi transposed [k][s]
    alignas(16) __shared__ float Sp[2 * 16 * 33];         // score partials [khalf][s][h]
    alignas(16) __shared__ unsigned short P[32 * 20];     // attn weights bf16 [h][s]
    __shared__ float alpha[32];

    // q fragments (pre-scaled by SCALE, split hi/lo) held in registers for whole block
    s16x8 qh[8], ql[8];
    {
        const float* qp = ws + OFF_QABS + (size_t)(b * H_ + ni * 16 + ln) * KV_ + kh * 256 + quad * 8;
#pragma unroll
        for (int st = 0; st < 8; ++st) {
            const f32x4 v0 = *(const f32x4*)(qp + st * 32);
            const f32x4 v1 = *(const f32x4*)(qp + st * 32 + 4);
#pragma unroll
            for (int i = 0; i < 8; ++i) {
                const float xv = ((i < 4) ? v0[i] : v1[i - 4]) * SCALE_;
                const unsigned short hi = f2bf(xv);
                qh[st][i] = (short)hi;
                ql[st][i] = (short)f2bf(xv - bf2f(hi));
            }
        }
    }

    f32x4 cacc[16];
#pragma unroll
    for (int i = 0; i < 16; ++i) cacc[i] = (f32x4){0.f, 0.f, 0.f, 0.f};
    float m_run = -1e30f, l_run = 0.f;

    for (int sub = 0; sub < 8; ++sub) {
        const int s0 = sc * 128 + sub * 16;
        // ---- stage 16 c rows: global fp32 -> LDS bf16 hi/lo + transposed hi
        {
            const int r = t >> 4, cb = (t & 15) * 32;
            const int sg = s0 + r;
            const float* src = (sg == PAST_) ? (ws + OFF_CNEW + (size_t)b * KV_)
                                             : (past_c + ((size_t)b * PAST_ + sg) * KV_);
#pragma unroll
            for (int i = 0; i < 8; ++i) {
                const int k = cb + i * 4;
                const f32x4 v = *(const f32x4*)(src + k);
                s16x4 hi4, lo4;
#pragma unroll
                for (int e = 0; e < 4; ++e) {
                    const unsigned short hh = f2bf(v[e]);
                    hi4[e] = (short)hh;
                    lo4[e] = (short)f2bf(v[e] - bf2f(hh));
                    cT[(k + e) * 20 + r] = hh;
                }
                *(s16x4*)&ch[r * 520 + k] = hi4;
                *(s16x4*)&cl[r * 520 + k] = lo4;
            }
        }
        __syncthreads();
        // ---- scores^T: D[s][h] = sum_k c[s][k] * q[h][k], split precision (3 MFMAs)
        {
            f32x4 sacc = {0.f, 0.f, 0.f, 0.f};
#pragma unroll
            for (int st = 0; st < 8; ++st) {
                const int ko = kh * 256 + st * 32 + quad * 8;
                const s16x8 ah = *(const s16x8*)&ch[ln * 520 + ko];
                const s16x8 al = *(const s16x8*)&cl[ln * 520 + ko];
                sacc = __builtin_amdgcn_mfma_f32_16x16x32_bf16(ah, qh[st], sacc, 0, 0, 0);
                sacc = __builtin_amdgcn_mfma_f32_16x16x32_bf16(ah, ql[st], sacc, 0, 0, 0);
                sacc = __builtin_amdgcn_mfma_f32_16x16x32_bf16(al, qh[st], sacc, 0, 0, 0);
            }
#pragma unroll
            for (int r = 0; r < 4; ++r)
                Sp[kh * 528 + (quad * 4 + r) * 33 + ni * 16 + ln] = sacc[r];
        }
        __syncthreads();
        // ---- online softmax (one half-wave; thread t = head h)
        if (t < 32) {
            const int h = t;
            float sv[16];
            float msub = -1e30f;
#pragma unroll
            for (int s = 0; s < 16; ++s) {
                sv[s] = Sp[s * 33 + h] + Sp[528 + s * 33 + h];
                msub = fmaxf(msub, sv[s]);
            }
            const float m_new = fmaxf(m_run, msub);
            const float al_ = __expf(m_run - m_new);
            float lsum = 0.f;
#pragma unroll
            for (int s = 0; s < 16; s += 2) {
                const float p0 = __expf(sv[s] - m_new);
                const float p1 = __expf(sv[s + 1] - m_new);
                lsum += p0 + p1;
                const unsigned pk = (unsigned)f2bf(p0) | ((unsigned)f2bf(p1) << 16);
                *(unsigned*)&P[h * 20 + s] = pk;
            }
            l_run = l_run * al_ + lsum;
            m_run = m_new;
            alpha[h] = al_;
        }
        __syncthreads();
        // ---- ctx^T accumulate: D[k][h] += sum_s cT[k][s] * P[h][s]  (K=16 MFMA)
        {
            const float av = alpha[ni * 16 + ln];
            const s16x4 bp = *(const s16x4*)&P[(ni * 16 + ln) * 20 + quad * 4];
#pragma unroll
            for (int ti = 0; ti < 16; ++ti) {
                const int krow = (kh * 16 + ti) * 16 + ln;
                const s16x4 ac = *(const s16x4*)&cT[krow * 20 + quad * 4];
                f32x4 cc = cacc[ti];
                cc[0] *= av; cc[1] *= av; cc[2] *= av; cc[3] *= av;
                cacc[ti] = __builtin_amdgcn_mfma_f32_16x16x16bf16_1k(ac, bp, cc, 0, 0, 0);
            }
        }
        __syncthreads();
    }
    // ---- write partial ctx (unnormalized, base m_run) + (m, l)
    {
        float* cp = ws + OFF_CTXP + ((size_t)(b * 64 + sc) * H_ + (ni * 16 + ln)) * KV_;
#pragma unroll
        for (int ti = 0; ti < 16; ++ti) {
            const int k0 = (kh * 16 + ti) * 16 + quad * 4;
            *(f32x4*)(cp + k0) = cacc[ti];
        }
    }
    if (t < 32) {
        float* mp = ws + OFF_ML + (size_t)(b * 64 + sc) * 64;
        mp[t] = m_run;
        mp[32 + t] = l_run;
    }
}

// ---------------- Kernel C: combine split-KV partials -> ctx[b][h][k]
__global__ __launch_bounds__(256) void k_comb(float* __restrict__ ws) {
    const int b = blockIdx.x >> 5, h = blockIdx.x & 31;
    const int t = threadIdx.x;
    __shared__ float ml[64], ll[64];
    if (t < 64) {
        const float* mp = ws + OFF_ML + (size_t)(b * 64 + t) * 64;
        ml[t] = mp[h];
        ll[t] = mp[32 + h];
    }
    __syncthreads();
    float M = -1e30f;
    for (int sc = 0; sc < 64; ++sc) M = fmaxf(M, ml[sc]);
    float L = 0.f;
    for (int sc = 0; sc < 64; ++sc) L += ll[sc] * __expf(ml[sc] - M);
    const float invL = 1.f / L;
    float a0 = 0.f, a1 = 0.f;
    for (int sc = 0; sc < 64; ++sc) {
        const float wgt = __expf(ml[sc] - M) * invL;
        const float* cp = ws + OFF_CTXP + ((size_t)(b * 64 + sc) * H_ + h) * KV_;
        a0 += wgt * cp[t];
        a1 += wgt * cp[256 + t];
    }
    float* o = ws + OFF_CTX + (size_t)(b * H_ + h) * KV_;
    o[t] = a0;
    o[256 + t] = a1;
}

// ---------------- Kernel D: ctx2[b][h*128+hd] = sum_k ctx[b][h][k] * w_v[k][h*128+hd]
__global__ __launch_bounds__(256) void k_vup(const float* __restrict__ wv, float* __restrict__ ws) {
    const int b = blockIdx.x >> 5, h = blockIdx.x & 31;
    const int t = threadIdx.x;
    alignas(16) __shared__ float cx[512];
    __shared__ float red[256];
    cx[t] = ws[OFF_CTX + (size_t)(b * H_ + h) * KV_ + t];
    cx[t + 256] = ws[OFF_CTX + (size_t)(b * H_ + h) * KV_ + t + 256];
    __syncthreads();
    const int khalf = t >> 7, hd = t & 127;
    const float* wp = wv + (size_t)(khalf * 256) * (H_ * HD_) + h * HD_ + hd;
    float acc = 0.f;
#pragma unroll 8
    for (int k = 0; k < 256; ++k)
        acc += cx[khalf * 256 + k] * wp[(size_t)k * (H_ * HD_)];
    red[t] = acc;
    __syncthreads();
    if (t < 128)
        ws[OFF_CTX2 + (size_t)b * (H_ * HD_) + h * HD_ + t] = red[t] + red[128 + t];
}

// ---------------- Kernel E: out[b][d] += sum_j ctx2[b][j] * w_o[j][d]
// grid (16 d-chunks, 16 j-chunks)
__global__ __launch_bounds__(256) void k_out(const float* __restrict__ wo,
                                             const float* __restrict__ ws,
                                             float* __restrict__ out) {
    const int dc = blockIdx.x, jc = blockIdx.y;
    const int t = threadIdx.x;
    alignas(16) __shared__ float c2[B_][256];
#pragma unroll
    for (int i = 0; i < 8; ++i) {
        const int e = t + i * 256;
        const int bb = e >> 8, jj = e & 255;
        c2[bb][jj] = ws[OFF_CTX2 + (size_t)bb * D_ + jc * 256 + jj];
    }
    __syncthreads();
    const int d = dc * 256 + t;
    float acc[B_] = {};
    for (int j = 0; j < 256; j += 4) {
        const float w0 = wo[(size_t)(jc * 256 + j) * D_ + d];
        const float w1 = wo[(size_t)(jc * 256 + j + 1) * D_ + d];
        const float w2 = wo[(size_t)(jc * 256 + j + 2) * D_ + d];
        const float w3 = wo[(size_t)(jc * 256 + j + 3) * D_ + d];
#pragma unroll
        for (int b = 0; b < B_; ++b) {
            const f32x4 cv = *(const f32x4*)&c2[b][j];
            acc[b] += cv[0] * w0 + cv[1] * w1 + cv[2] * w2 + cv[3] * w3;
        }
    }
#pragma unroll
    for (int b = 0; b < B_; ++b)
        atomicAdd(&out[b * D_ + d], acc[b]);
}

extern "C" void kernel_launch(void* const* d_in, const int* in_sizes, int n_in,
                              void* d_out, int out_size, void* d_ws, size_t ws_size,
                              hipStream_t stream) {
    const float* x      = (const float*)d_in[0];
    const float* past_c = (const float*)d_in[1];
    const float* aqk    = (const float*)d_in[2];
    const float* wc     = (const float*)d_in[3];
    const float* wv     = (const float*)d_in[4];
    const float* wo     = (const float*)d_in[5];
    float* out = (float*)d_out;
    float* ws  = (float*)d_ws;

    // zero accumulation targets (ws is poisoned before every launch)
    hipMemsetAsync(ws, 0, (size_t)OFF_ML * sizeof(float), stream);
    hipMemsetAsync(d_out, 0, (size_t)out_size * sizeof(float), stream);

    k_qabs<<<dim3(33, 8), 256, 0, stream>>>(x, aqk, wc, ws);
    k_attn<<<dim3(512), 256, 0, stream>>>(past_c, ws);
    k_comb<<<dim3(256), 256, 0, stream>>>(ws);
    k_vup<<<dim3(256), 256, 0, stream>>>(wv, ws);
    k_out<<<dim3(16, 16), 256, 0, stream>>>(wo, ws, out);
}

// Round 2
// 550.044 us; speedup vs baseline: 1.0817x; 1.0817x over previous
//
#include <hip/hip_runtime.h>
#include <stdint.h>

#define B_ 8
#define D_ 4096
#define H_ 32
#define HD_ 128
#define KV_ 512
#define PAST_ 8191
#define SCALE_ 0.08838834764831845f  // 128^-0.5

// workspace layout (float offsets)
#define OFF_QP   0u          // q partials   [16][8][32][512]
#define OFF_CP   2097152u    // c partials   [16][8][512]
#define OFF_QABS 2162688u    // q_abs        [8][32][512]
#define OFF_CNEW 2293760u    // c_new        [8][512]
#define OFF_ML   2297856u    // m,l          [8][64][64]
#define OFF_CTXP 2330624u    // ctx partials [8][64][32][512]
#define OFF_CTX2 10719232u   // ctx2         [8][4096]
// total 10752000 floats = 43 MB

typedef float f32x4 __attribute__((ext_vector_type(4)));
typedef float f32x2 __attribute__((ext_vector_type(2)));
typedef short s16x8 __attribute__((ext_vector_type(8)));
typedef short s16x4 __attribute__((ext_vector_type(4)));

__device__ __forceinline__ unsigned short f2bf(float f) {
    unsigned u = __float_as_uint(f);
    u = (u + 0x7FFFu + ((u >> 16) & 1u)) >> 16;
    return (unsigned short)u;
}
__device__ __forceinline__ float bf2f(unsigned short s) {
    return __uint_as_float(((unsigned)s) << 16);
}

// ---------------- Kernel A: partial q_abs / c_new GEMV, no atomics
// grid (33, 16): x = h (32 == compress), y = d-chunk of 256. 128 threads.
__global__ __launch_bounds__(128) void k_qabs(const float* __restrict__ x,
                                              const float* __restrict__ aqk,
                                              const float* __restrict__ wc,
                                              float* __restrict__ ws) {
    const int h = blockIdx.x;
    const int dc = blockIdx.y;
    const int t = threadIdx.x;
    alignas(16) __shared__ float x_lds[B_][256];
    for (int i = t; i < 512; i += 128) {  // 512 f32x4 groups
        const int b = i >> 6, g = i & 63;
        *(f32x4*)&x_lds[b][g * 4] = *(const f32x4*)(x + (size_t)b * D_ + dc * 256 + g * 4);
    }
    __syncthreads();
    const float* A = (h < H_) ? (aqk + (size_t)h * D_ * KV_) : wc;
    A += ((size_t)dc * 256) * KV_ + t * 4;

    f32x4 acc[B_];
#pragma unroll
    for (int b = 0; b < B_; ++b) acc[b] = (f32x4){0.f, 0.f, 0.f, 0.f};

#pragma unroll 2
    for (int dd = 0; dd < 256; dd += 4) {
        const f32x4 a0 = *(const f32x4*)(A + (size_t)(dd + 0) * KV_);
        const f32x4 a1 = *(const f32x4*)(A + (size_t)(dd + 1) * KV_);
        const f32x4 a2 = *(const f32x4*)(A + (size_t)(dd + 2) * KV_);
        const f32x4 a3 = *(const f32x4*)(A + (size_t)(dd + 3) * KV_);
#pragma unroll
        for (int b = 0; b < B_; ++b) {
            const f32x4 xq = *(const f32x4*)&x_lds[b][dd];
            acc[b] += xq.x * a0 + xq.y * a1 + xq.z * a2 + xq.w * a3;
        }
    }
#pragma unroll
    for (int b = 0; b < B_; ++b) {
        float* dst = (h < H_)
            ? (ws + OFF_QP + (size_t)dc * 131072u + (size_t)(b * H_ + h) * KV_ + t * 4)
            : (ws + OFF_CP + (size_t)dc * 4096u + (size_t)b * KV_ + t * 4);
        *(f32x4*)dst = acc[b];
    }
}

// ---------------- Kernel A2: reduce 16 partial slices
// grid 264: blocks 0..255 = (b,h) q rows; 256..263 = c_new rows
__global__ __launch_bounds__(256) void k_qred(float* __restrict__ ws) {
    const int bx = blockIdx.x;
    const int t = threadIdx.x;
    if (bx < 256) {
        const int b = bx >> 5, h = bx & 31;
        const size_t row = (size_t)(b * H_ + h) * KV_;
        f32x2 s = {0.f, 0.f};
#pragma unroll
        for (int p = 0; p < 16; ++p) {
            const f32x2 v = *(const f32x2*)(ws + OFF_QP + (size_t)p * 131072u + row + 2 * t);
            s[0] += v[0]; s[1] += v[1];
        }
        *(f32x2*)(ws + OFF_QABS + row + 2 * t) = s;
    } else {
        const int b = bx - 256;
        f32x2 s = {0.f, 0.f};
#pragma unroll
        for (int p = 0; p < 16; ++p) {
            const f32x2 v = *(const f32x2*)(ws + OFF_CP + (size_t)p * 4096u + (size_t)b * KV_ + 2 * t);
            s[0] += v[0]; s[1] += v[1];
        }
        *(f32x2*)(ws + OFF_CNEW + (size_t)b * KV_ + 2 * t) = s;
    }
}

// ---------------- Kernel B: split-KV flash attention over compressed cache
// grid 512: block = (b, sc) ; chunk = 128 s, sub-chunks of 16 s
__global__ __launch_bounds__(256, 2) void k_attn(const float* __restrict__ past_c,
                                                 float* __restrict__ ws) {
    const int bx = blockIdx.x;
    const int b = bx >> 6, sc = bx & 63;
    const int t = threadIdx.x;
    const int w = t >> 6, lane = t & 63, quad = lane >> 4, ln = lane & 15;
    const int ni = w & 1, kh = w >> 1;

    alignas(16) __shared__ unsigned short ch[16 * 520];   // c hi, row-major [s][k]
    alignas(16) __shared__ unsigned short cl[16 * 520];   // c lo
    alignas(16) __shared__ unsigned short cT[512 * 20];   // c hi transposed [k][s^swz]
    alignas(16) __shared__ float Sp[2 * 16 * 33];         // score partials [khalf][s][h]
    alignas(16) __shared__ unsigned short P[32 * 20];     // attn weights bf16 [h][s]
    __shared__ float alpha[32];

    // q fragments (pre-scaled by SCALE, split hi/lo) held in registers
    s16x8 qh[8], ql[8];
    {
        const float* qp = ws + OFF_QABS + (size_t)(b * H_ + ni * 16 + ln) * KV_ + kh * 256 + quad * 8;
#pragma unroll
        for (int st = 0; st < 8; ++st) {
            const f32x4 v0 = *(const f32x4*)(qp + st * 32);
            const f32x4 v1 = *(const f32x4*)(qp + st * 32 + 4);
#pragma unroll
            for (int i = 0; i < 8; ++i) {
                const float xv = ((i < 4) ? v0[i] : v1[i - 4]) * SCALE_;
                const unsigned short hi = f2bf(xv);
                qh[st][i] = (short)hi;
                ql[st][i] = (short)f2bf(xv - bf2f(hi));
            }
        }
    }

    f32x4 cacc[16];
#pragma unroll
    for (int i = 0; i < 16; ++i) cacc[i] = (f32x4){0.f, 0.f, 0.f, 0.f};
    float m_run = -1e30f, l_run = 0.f;

    for (int sub = 0; sub < 8; ++sub) {
        const int s0 = sc * 128 + sub * 16;
        // ---- stage 16 c rows: lane owns 4-consecutive-col chunks (bank-balanced)
        {
            const int r = t >> 4, m = t & 15;
            const int sg = s0 + r;
            const float* src = (sg == PAST_) ? (ws + OFF_CNEW + (size_t)b * KV_)
                                             : (past_c + ((size_t)b * PAST_ + sg) * KV_);
#pragma unroll
            for (int i = 0; i < 8; ++i) {
                const int k = m * 4 + i * 64;
                const f32x4 v = *(const f32x4*)(src + k);
                s16x4 hi4, lo4;
#pragma unroll
                for (int e = 0; e < 4; ++e) {
                    const unsigned short hh = f2bf(v[e]);
                    hi4[e] = (short)hh;
                    lo4[e] = (short)f2bf(v[e] - bf2f(hh));
                    const int kk = k + e;
                    cT[kk * 20 + (r ^ ((((kk) >> 4) & 3) << 2))] = hh;  // swizzled
                }
                *(s16x4*)&ch[r * 520 + k] = hi4;
                *(s16x4*)&cl[r * 520 + k] = lo4;
            }
        }
        __syncthreads();
        // ---- scores^T: D[s][h] = sum_k c[s][k] * q[h][k], split precision
        {
            f32x4 sacc = {0.f, 0.f, 0.f, 0.f};
#pragma unroll
            for (int st = 0; st < 8; ++st) {
                const int ko = kh * 256 + st * 32 + quad * 8;
                const s16x8 ah = *(const s16x8*)&ch[ln * 520 + ko];
                const s16x8 al = *(const s16x8*)&cl[ln * 520 + ko];
                sacc = __builtin_amdgcn_mfma_f32_16x16x32_bf16(ah, qh[st], sacc, 0, 0, 0);
                sacc = __builtin_amdgcn_mfma_f32_16x16x32_bf16(ah, ql[st], sacc, 0, 0, 0);
                sacc = __builtin_amdgcn_mfma_f32_16x16x32_bf16(al, qh[st], sacc, 0, 0, 0);
            }
#pragma unroll
            for (int r = 0; r < 4; ++r)
                Sp[kh * 528 + (quad * 4 + r) * 33 + ni * 16 + ln] = sacc[r];
        }
        __syncthreads();
        // ---- online softmax (thread t = head h)
        if (t < 32) {
            const int h = t;
            float sv[16];
            float msub = -1e30f;
#pragma unroll
            for (int s = 0; s < 16; ++s) {
                sv[s] = Sp[s * 33 + h] + Sp[528 + s * 33 + h];
                msub = fmaxf(msub, sv[s]);
            }
            const float m_new = fmaxf(m_run, msub);
            const float al_ = __expf(m_run - m_new);
            float lsum = 0.f;
#pragma unroll
            for (int s = 0; s < 16; s += 2) {
                const float p0 = __expf(sv[s] - m_new);
                const float p1 = __expf(sv[s + 1] - m_new);
                lsum += p0 + p1;
                const unsigned pk = (unsigned)f2bf(p0) | ((unsigned)f2bf(p1) << 16);
                *(unsigned*)&P[h * 20 + s] = pk;
            }
            l_run = l_run * al_ + lsum;
            m_run = m_new;
            alpha[h] = al_;
        }
        __syncthreads();
        // ---- ctx^T accumulate: D[k][h] += sum_s cT[k][s] * P[h][s]
        {
            const float av = alpha[ni * 16 + ln];
            const s16x4 bp = *(const s16x4*)&P[(ni * 16 + ln) * 20 + quad * 4];
#pragma unroll
            for (int ti = 0; ti < 16; ++ti) {
                const int krow = (kh * 16 + ti) * 16 + ln;
                const int sg2 = (quad ^ ((krow >> 4) & 3)) << 2;   // un-swizzle
                const s16x4 ac = *(const s16x4*)&cT[krow * 20 + sg2];
                f32x4 cc = cacc[ti];
                cc[0] *= av; cc[1] *= av; cc[2] *= av; cc[3] *= av;
                cacc[ti] = __builtin_amdgcn_mfma_f32_16x16x16bf16_1k(ac, bp, cc, 0, 0, 0);
            }
        }
        __syncthreads();
    }
    // ---- write partial ctx (unnormalized, base m_run) + (m, l)
    {
        float* cp = ws + OFF_CTXP + ((size_t)(b * 64 + sc) * H_ + (ni * 16 + ln)) * KV_;
#pragma unroll
        for (int ti = 0; ti < 16; ++ti) {
            const int k0 = (kh * 16 + ti) * 16 + quad * 4;
            *(f32x4*)(cp + k0) = cacc[ti];
        }
    }
    if (t < 32) {
        float* mp = ws + OFF_ML + (size_t)(b * 64 + sc) * 64;
        mp[t] = m_run;
        mp[32 + t] = l_run;
    }
}

// ---------------- Kernel C: fused combine + v_up. grid 256 = (b,h)
__global__ __launch_bounds__(256) void k_cv(const float* __restrict__ wv,
                                            float* __restrict__ ws) {
    const int b = blockIdx.x >> 5, h = blockIdx.x & 31;
    const int t = threadIdx.x;
    __shared__ float ml[64], ll[64], wgt[64];
    alignas(16) __shared__ float cx[512];
    alignas(16) __shared__ float red[8][128];
    if (t < 64) {
        const float* mp = ws + OFF_ML + (size_t)(b * 64 + t) * 64;
        ml[t] = mp[h];
        ll[t] = mp[32 + h];
    }
    __syncthreads();
    float M = -1e30f;
    for (int s = 0; s < 64; ++s) M = fmaxf(M, ml[s]);
    if (t < 64) wgt[t] = __expf(ml[t] - M);
    __syncthreads();
    float L = 0.f;
    for (int s = 0; s < 64; ++s) L += ll[s] * wgt[s];
    const float invL = 1.f / L;
    f32x2 acc = {0.f, 0.f};
    for (int s = 0; s < 64; ++s) {
        const float f = wgt[s];
        const f32x2 v = *(const f32x2*)(ws + OFF_CTXP + ((size_t)(b * 64 + s) * H_ + h) * KV_ + 2 * t);
        acc[0] += f * v[0];
        acc[1] += f * v[1];
    }
    *(f32x2*)&cx[2 * t] = (f32x2){acc[0] * invL, acc[1] * invL};
    __syncthreads();
    // v_up: out[hd] = sum_k cx[k] * wv[k][h*128+hd]
    const int r = t >> 5, c = (t & 31) * 4;
    f32x4 a4 = {0.f, 0.f, 0.f, 0.f};
    for (int kb = 0; kb < 64; ++kb) {
        const int k = kb * 8 + r;
        const f32x4 w4 = *(const f32x4*)(wv + (size_t)k * (H_ * HD_) + h * HD_ + c);
        a4 += cx[k] * w4;
    }
    *(f32x4*)&red[r][c] = a4;
    __syncthreads();
    if (t < 128) {
        float s = 0.f;
#pragma unroll
        for (int rr = 0; rr < 8; ++rr) s += red[rr][t];
        ws[OFF_CTX2 + (size_t)b * D_ + h * HD_ + t] = s;
    }
}

// ---------------- Kernel E: out[b][d] += sum_j ctx2[b][j] * w_o[j][d]
// grid (16 d-chunks, 16 j-chunks)
__global__ __launch_bounds__(256) void k_out(const float* __restrict__ wo,
                                             const float* __restrict__ ws,
                                             float* __restrict__ out) {
    const int dc = blockIdx.x, jc = blockIdx.y;
    const int t = threadIdx.x;
    alignas(16) __shared__ float c2[B_][256];
#pragma unroll
    for (int i = 0; i < 8; ++i) {
        const int e = t + i * 256;
        const int bb = e >> 8, jj = e & 255;
        c2[bb][jj] = ws[OFF_CTX2 + (size_t)bb * D_ + jc * 256 + jj];
    }
    __syncthreads();
    const int d = dc * 256 + t;
    float acc[B_] = {};
    for (int j = 0; j < 256; j += 8) {
        float wreg[8];
#pragma unroll
        for (int u = 0; u < 8; ++u)
            wreg[u] = wo[(size_t)(jc * 256 + j + u) * D_ + d];
#pragma unroll
        for (int b = 0; b < B_; ++b) {
            const f32x4 c0 = *(const f32x4*)&c2[b][j];
            const f32x4 c1 = *(const f32x4*)&c2[b][j + 4];
            acc[b] += c0[0] * wreg[0] + c0[1] * wreg[1] + c0[2] * wreg[2] + c0[3] * wreg[3]
                    + c1[0] * wreg[4] + c1[1] * wreg[5] + c1[2] * wreg[6] + c1[3] * wreg[7];
        }
    }
#pragma unroll
    for (int b = 0; b < B_; ++b)
        atomicAdd(&out[b * D_ + d], acc[b]);
}

extern "C" void kernel_launch(void* const* d_in, const int* in_sizes, int n_in,
                              void* d_out, int out_size, void* d_ws, size_t ws_size,
                              hipStream_t stream) {
    const float* x      = (const float*)d_in[0];
    const float* past_c = (const float*)d_in[1];
    const float* aqk    = (const float*)d_in[2];
    const float* wc     = (const float*)d_in[3];
    const float* wv     = (const float*)d_in[4];
    const float* wo     = (const float*)d_in[5];
    float* out = (float*)d_out;
    float* ws  = (float*)d_ws;

    hipMemsetAsync(d_out, 0, (size_t)out_size * sizeof(float), stream);

    k_qabs<<<dim3(33, 16), 128, 0, stream>>>(x, aqk, wc, ws);
    k_qred<<<dim3(264), 256, 0, stream>>>(ws);
    k_attn<<<dim3(512), 256, 0, stream>>>(past_c, ws);
    k_cv<<<dim3(256), 256, 0, stream>>>(wv, ws);
    k_out<<<dim3(16, 16), 256, 0, stream>>>(wo, ws, out);
}